// Round 3
// 139.911 us; speedup vs baseline: 1.0467x; 1.0467x over previous
//
#include <hip/hip_runtime.h>
#include <hip/hip_bf16.h>

// FeatureAlign deformable 3x3 conv, G=4, PAD=1.
// R11 = R9/R10 with the compile fix: __builtin_shufflevector needs parse-time
// constant indices, so the commit() corner pairs are now read through f16x2
// pointer views (constant after full unroll). Changes vs R8 remain:
//  (1) fa_prep transpose rewritten as LDS-staged tile transpose (32hw x 256c,
//      XOR-swizzled LDS, coalesced 512B output stores).
//  (2) whole sampled pipeline bf16 -> f16: interp in packed f16
//      (v_pk_fma_f16, weights already f16x2 in meta), MFMA 16x16x32_f16,
//      32-bit gather offsets, B-frag ds_reads hoisted before commit().
// Grid/pipeline of fa_main otherwise unchanged (512 blk x 512 thr, 2 blk/CU).

#define Bn   8
#define CIN  256
#define COUT 256
#define Hn   64
#define Wn   64
#define Gn   4
#define Kn   9
#define CPG  64
#define GK   36

typedef float    f32x4 __attribute__((ext_vector_type(4)));
typedef _Float16 f16x2 __attribute__((ext_vector_type(2)));
typedef _Float16 f16x8 __attribute__((ext_vector_type(8)));

// ---------------------------------------------------------------------------
// Fused prep.
//  blocks [0, 1024):        x (b,c,y,x) f32 -> xt (b, y*64+x, c) f16 [NHWC]
//                           via LDS-staged transpose, 32hw x 256c per block.
//  blocks [1024, 1024+32):  w_deform -> fragment-linear f16 wfrag
// ---------------------------------------------------------------------------
#define SWPAD 1156
#define HWT   32
__global__ void fa_prep(const float* __restrict__ x, const float* __restrict__ w,
                        _Float16* __restrict__ xt, _Float16* __restrict__ wfrag) {
    const int bid = blockIdx.x, t = threadIdx.x;
    __shared__ __align__(16) _Float16 spool[16 * SWPAD];   // 36,992 B (shared by both roles)
    if (bid < 1024) {
        _Float16* sT = spool;                              // uses 32*256 = 8192 elems
        const int b = bid >> 7, tile = bid & 127;
        const int hw0 = tile * HWT;
        // phase 1: coalesced f32 reads, f16 convert, swizzled LDS scatter.
        // thread: s = c-within-32, hwq = which float4 of the 32-hw row.
        const int s = t >> 3, hwq = t & 7;
#pragma unroll
        for (int it = 0; it < 8; it++) {
            int c = it * 32 + s;
            float4 v = *(const float4*)(x + (((size_t)(b * CIN + c)) << 12) + hw0 + hwq * 4);
            const float* vf = (const float*)&v;
#pragma unroll
            for (int j = 0; j < 4; j++) {
                int hw = hwq * 4 + j;
                // swizzle: column c XOR ((hw>>2)&7)<<3 -> 2-way-max bank aliasing
                sT[hw * 256 + (c ^ (hwq << 3))] = (_Float16)vf[j];
            }
        }
        __syncthreads();
        // phase 2: b128 LDS reads (conflict-free: full permuted rows),
        // 512B-contiguous global stores.
        const int cg = t & 31, hwr = t >> 5;
#pragma unroll
        for (int it = 0; it < 4; it++) {
            int hw = it * 8 + hwr;
            int q = hw >> 2;                               // 0..7
            f16x8 v = *(const f16x8*)&sT[hw * 256 + ((cg ^ q) << 3)];
            *(f16x8*)&xt[(((size_t)b << 12) + hw0 + hw) * 256 + cg * 8] = v;
        }
    } else {
        _Float16* sw = spool;
        const int mt = (bid - 1024) >> 1, gh = (bid - 1024) & 1;
        const int o0 = mt * 16, g0 = gh * 2;
        const int r = t >> 4, tr = t & 15;
        const float* wp = w + (size_t)(o0 + r) * (CIN * Kn) + g0 * (CPG * Kn);
#pragma unroll
        for (int it = 0; it < 18; it++) {
            int off = it * 64 + tr * 4;
            float4 v = *(const float4*)(wp + off);
            _Float16* d = &sw[r * SWPAD + off];
            d[0] = (_Float16)v.x; d[1] = (_Float16)v.y;
            d[2] = (_Float16)v.z; d[3] = (_Float16)v.w;
        }
        __syncthreads();
#pragma unroll
        for (int it = 0; it < 9; it++) {
            int chunk = it * 256 + t;
            int lane = chunk & 63, ks = (chunk >> 6) & 1, gkl = chunk >> 7;
            int gl = gkl / Kn, k = gkl - gl * Kn;
            int gk = g0 * Kn + gkl;
            int ol = lane & 15;
            int cbase = ks * 32 + (lane >> 4) * 8;
            f16x8 v;
#pragma unroll
            for (int j = 0; j < 8; j++)
                v[j] = sw[ol * SWPAD + (gl * CPG + cbase + j) * Kn + k];
            *(f16x8*)&wfrag[(((size_t)gk * 16 + mt) * 2 + ks) * 512 + lane * 8] = v;
        }
    }
}

// ---------------------------------------------------------------------------
// Main: 512 blocks x 512 threads. Block = bp*128 + h*2 + wh.
// N = 64 (2 b x 32 w); M = 256 over 8 waves (32 o-rows each). K = 36*64.
// ---------------------------------------------------------------------------
__global__ __launch_bounds__(512, 4)
void fa_main(const _Float16* __restrict__ xt, const float* __restrict__ shp,
             const float* __restrict__ w_off, const _Float16* __restrict__ wfrag,
             float* __restrict__ out) {
    const int blk = blockIdx.x;
    const int bp = blk >> 7, h = (blk >> 1) & 63, wh = blk & 1;
    const int w0 = wh * 32;
    const int t = threadIdx.x;
    const int wid = t >> 6, lane = t & 63;
    const int col = lane & 15, quad = lane >> 4;
    const int cg = t & 7, nl = (t >> 3) & 63;

    __shared__ __align__(16) int4 s_meta[GK * 64];        // 36864 B
    __shared__ __align__(16) _Float16 sB[2][64 * 64];     // 16384 B
    __shared__ float s_shp[2 * 4 * 32];                   // 1024 B
    __shared__ float s_woff[GK * 8];                      // 1152 B

    // ---- stage shp slice (2 b x 4 c x 32 w at row h) + ALL 288 w_off ----
    if (t < 256) {
        int bb = t >> 7, c = (t >> 5) & 3, wl = t & 31;
        s_shp[t] = shp[(((bp * 2 + bb) * 4 + c) << 12) + h * Wn + w0 + wl];
    }
    for (int u = t; u < GK * 8; u += 512) s_woff[u] = w_off[u];
    __syncthreads();

    // ---- meta: one 16B record per (gk, n) ----
    for (int i = t; i < GK * 64; i += 512) {
        int gk = i >> 6, n = i & 63;
        int bb = n >> 5, wl = n & 31;
        int g = gk / Kn, k = gk - g * Kn;
        int ky = k / 3, kx = k - ky * 3;
        float dy = 0.f, dx = 0.f;
#pragma unroll
        for (int c = 0; c < 4; c++) {
            float sv = s_shp[(bb * 4 + c) * 32 + wl];
            dy = fmaf(s_woff[gk * 8 + c],     sv, dy);
            dx = fmaf(s_woff[gk * 8 + 4 + c], sv, dx);
        }
        float py = (float)(h + ky - 1) + dy;
        float px = (float)(w0 + wl + kx - 1) + dx;
        float y0 = floorf(py), x0 = floorf(px);
        float fy = py - y0, fx = px - x0;
        int iy = (int)y0, ix = (int)x0;
        bool y0v = (unsigned)iy       < (unsigned)Hn;
        bool y1v = (unsigned)(iy + 1) < (unsigned)Hn;
        bool x0v = (unsigned)ix       < (unsigned)Wn;
        bool x1v = (unsigned)(ix + 1) < (unsigned)Wn;
        int yc0 = min(max(iy, 0), Hn - 1), yc1 = min(max(iy + 1, 0), Hn - 1);
        int xc0 = min(max(ix, 0), Wn - 1), xc1 = min(max(ix + 1, 0), Wn - 1);
        int l00 = yc0 * Wn + xc0, l01 = yc0 * Wn + xc1;
        int l10 = yc1 * Wn + xc0, l11 = yc1 * Wn + xc1;
        float wy1 = fy, wy0 = 1.f - fy, wx1 = fx, wx0 = 1.f - fx;
        float w00 = (y0v && x0v) ? wy0 * wx0 : 0.f;
        float w01 = (y0v && x1v) ? wy0 * wx1 : 0.f;
        float w10 = (y1v && x0v) ? wy1 * wx0 : 0.f;
        float w11 = (y1v && x1v) ? wy1 * wx1 : 0.f;
        f16x2 p0, p1;
        p0.x = (_Float16)w00; p0.y = (_Float16)w01;
        p1.x = (_Float16)w10; p1.y = (_Float16)w11;
        s_meta[i] = make_int4(l00 | (l01 << 16), l10 | (l11 << 16),
                              __builtin_bit_cast(int, p0),
                              __builtin_bit_cast(int, p1));
    }

    f16x8 c4[4];
    int2  amv;
    // per-thread 32-bit element base inside xt: b*2^20 + cg*8 (g added per gk)
    const unsigned nBase = ((unsigned)(bp * 2 + (nl >> 5)) << 20) + (unsigned)cg * 8u;

    auto issue = [&](int gk) {
        int4 mv = s_meta[gk * 64 + nl];
        amv.x = mv.z; amv.y = mv.w;
        unsigned g = (unsigned)gk / (unsigned)Kn;
        unsigned base = nBase + g * 64u;
        c4[0] = *(const f16x8*)(xt + base + (((unsigned)mv.x & 0xffffu) << 8));
        c4[1] = *(const f16x8*)(xt + base + (((unsigned)mv.x >> 16)     << 8));
        c4[2] = *(const f16x8*)(xt + base + (((unsigned)mv.y & 0xffffu) << 8));
        c4[3] = *(const f16x8*)(xt + base + (((unsigned)mv.y >> 16)     << 8));
    };
    auto commit = [&](int buf) {
        f16x2 wv0 = __builtin_bit_cast(f16x2, amv.x);     // {w00, w01}
        f16x2 wv1 = __builtin_bit_cast(f16x2, amv.y);     // {w10, w11}
        f16x2 w00 = __builtin_shufflevector(wv0, wv0, 0, 0);
        f16x2 w01 = __builtin_shufflevector(wv0, wv0, 1, 1);
        f16x2 w10 = __builtin_shufflevector(wv1, wv1, 0, 0);
        f16x2 w11 = __builtin_shufflevector(wv1, wv1, 1, 1);
        // f16x2 views of the four corner vectors (constant index post-unroll)
        const f16x2* a0p = (const f16x2*)&c4[0];
        const f16x2* a1p = (const f16x2*)&c4[1];
        const f16x2* a2p = (const f16x2*)&c4[2];
        const f16x2* a3p = (const f16x2*)&c4[3];
        f16x8 r;
        f16x2* rp = (f16x2*)&r;
#pragma unroll
        for (int p = 0; p < 4; p++) {
            f16x2 rv = w00 * a0p[p] + w01 * a1p[p]
                     + w10 * a2p[p] + w11 * a3p[p];        // v_pk_fma_f16
            rp[p] = rv;
        }
        *(f16x8*)&sB[buf][(nl * 8 + (cg ^ (nl & 7))) * 8] = r;
    };

    f32x4 acc[2][4];
#pragma unroll
    for (int mt = 0; mt < 2; mt++)
#pragma unroll
        for (int nt = 0; nt < 4; nt++) acc[mt][nt] = (f32x4){0.f, 0.f, 0.f, 0.f};

    __syncthreads();            // meta visible

    issue(0);
    commit(0);                  // sB[0] = tile 0
    issue(1);                   // corners(1) in regs
    __syncthreads();

    for (int gk = 0; gk < GK; gk++) {
        const int buf = gk & 1;
        // 1) A-frags for THIS gk (oldest vm loads; corner loads stay in
        //    flight across the MFMA's wait)
        const _Float16* wbase = wfrag + (((size_t)gk * 16 + wid * 2) * 2) * 512;
        f16x8 af[2][2];
#pragma unroll
        for (int ks = 0; ks < 2; ks++)
#pragma unroll
            for (int mt = 0; mt < 2; mt++)
                af[ks][mt] = *(const f16x8*)(wbase + ((size_t)(mt * 2 + ks) * 64 + lane) * 8);
        // 2) B-frags EARLY (sB[buf] written before last barrier) so the
        //    ds_read latency hides under the interp VALU below
        f16x8 bfv[2][4];
#pragma unroll
        for (int ks = 0; ks < 2; ks++)
#pragma unroll
            for (int nt = 0; nt < 4; nt++) {
                int n = nt * 16 + col;
                int cq8 = ks * 4 + quad;
                bfv[ks][nt] = *(const f16x8*)&sB[buf][(n * 8 + (cq8 ^ (n & 7))) * 8];
            }
        // 3) interp gk+1 (corners landed last iter) -> other buffer
        if (gk + 1 < GK) commit(buf ^ 1);
        // 4) corner loads for gk+2
        if (gk + 2 < GK) issue(gk + 2);
        // 5) MFMA
#pragma unroll
        for (int ks = 0; ks < 2; ks++)
#pragma unroll
            for (int mt = 0; mt < 2; mt++)
#pragma unroll
                for (int nt = 0; nt < 4; nt++)
                    acc[mt][nt] = __builtin_amdgcn_mfma_f32_16x16x32_f16(
                        af[ks][mt], bfv[ks][nt], acc[mt][nt], 0, 0, 0);
        __syncthreads();
    }

    // ---- epilogue: o = wid*32 + mt*16 + quad*4 + r ; n = nt*16 + col ----
#pragma unroll
    for (int mt = 0; mt < 2; mt++)
#pragma unroll
        for (int r = 0; r < 4; r++) {
            int o = wid * 32 + mt * 16 + quad * 4 + r;
#pragma unroll
            for (int nt = 0; nt < 4; nt++) {
                int n = nt * 16 + col;
                int b = bp * 2 + (n >> 5);
                int w = w0 + (n & 31);
                out[(((size_t)(b * COUT + o)) << 12) + h * Wn + w] =
                    fmaxf(acc[mt][nt][r], 0.f);
            }
        }
}

// ---------------------------------------------------------------------------
extern "C" void kernel_launch(void* const* d_in, const int* in_sizes, int n_in,
                              void* d_out, int out_size, void* d_ws, size_t ws_size,
                              hipStream_t stream) {
    const float* x     = (const float*)d_in[0];
    const float* shp   = (const float*)d_in[1];
    const float* w_off = (const float*)d_in[2];
    const float* w_def = (const float*)d_in[3];
    float* out = (float*)d_out;
    _Float16* wfrag = (_Float16*)d_ws;                       // 1.18 MB
    _Float16* xt    = (_Float16*)((char*)d_ws + (2u << 20)); // 16.8 MB

    fa_prep<<<1024 + 32, 256, 0, stream>>>(x, w_def, xt, wfrag);
    fa_main<<<512, 512, 0, stream>>>(xt, shp, w_off, wfrag, out);
}